// Round 1
// baseline (1275.568 us; speedup 1.0000x reference)
//
#include <hip/hip_runtime.h>

#define WG 256

// ---------------------------------------------------------------------------
// Edge-index dtype probe: if input is int64 (little-endian, values < 2^31),
// every odd 32-bit word of the first 256 entries is 0. For int32 random
// indices in [0,1e5) that is statistically impossible.
// ---------------------------------------------------------------------------
__global__ __launch_bounds__(WG) void k_detect(const unsigned int* __restrict__ ei,
                                               int* __restrict__ flag) {
  __shared__ int nz;
  if (threadIdx.x == 0) nz = 0;
  __syncthreads();
  unsigned int w = ei[threadIdx.x * 2 + 1];
  if (w != 0u) atomicAdd(&nz, 1);
  __syncthreads();
  if (threadIdx.x == 0) *flag = (nz == 0) ? 1 : 0;  // 1 => int64 layout
}

__global__ __launch_bounds__(WG) void k_convert(const int* __restrict__ ei,
                                                const int* __restrict__ flag,
                                                int* __restrict__ src,
                                                int* __restrict__ dst, int E) {
  int e = blockIdx.x * WG + threadIdx.x;
  if (e >= E) return;
  if (*flag) {  // int64: low words at 2*idx
    src[e] = ei[2 * e];
    dst[e] = ei[2 * (E + e)];
  } else {
    src[e] = ei[e];
    dst[e] = ei[E + e];
  }
}

// ---------------------------------------------------------------------------
// Degree (init 1.0 accounts for the appended self-loop) and deg^-1/2
// ---------------------------------------------------------------------------
__global__ __launch_bounds__(WG) void k_deg_init(float* __restrict__ deg, int N) {
  int i = blockIdx.x * WG + threadIdx.x;
  if (i < N) deg[i] = 1.0f;
}

__global__ __launch_bounds__(WG) void k_deg_count(const int* __restrict__ dst,
                                                  float* __restrict__ deg, int E) {
  int e = blockIdx.x * WG + threadIdx.x;
  if (e < E) atomicAdd(&deg[dst[e]], 1.0f);
}

__global__ __launch_bounds__(WG) void k_dinv(const float* __restrict__ deg,
                                             float* __restrict__ dinv, int N) {
  int i = blockIdx.x * WG + threadIdx.x;
  if (i < N) dinv[i] = rsqrtf(deg[i]);
}

// ---------------------------------------------------------------------------
// GEMM1: hpre1[n][64] = x[n][128] @ W1[128][64]
// Epilogue also writes agg1 = hpre1 * dinv[n]^2 (self-loop init).
// 64-node tile; x tile XOR-swizzled in LDS (conflict-free b128 reads);
// W1 (32KB) fully in LDS. Exactly 64KB static LDS -> 2 blocks/CU.
// ---------------------------------------------------------------------------
__global__ __launch_bounds__(WG) void k_gemm1(const float* __restrict__ x,
                                              const float* __restrict__ W1,
                                              const float* __restrict__ dinv,
                                              float* __restrict__ hpre1,
                                              float* __restrict__ agg1, int N) {
  __shared__ float xs[64 * 128];
  __shared__ float w1s[128 * 64];
  const int tid = threadIdx.x;
  const int n0 = blockIdx.x * 64;

  for (int v = tid; v < 2048; v += WG)
    *(float4*)&w1s[v * 4] = ((const float4*)W1)[v];
  for (int v = tid; v < 2048; v += WG) {
    int row = v >> 5, c4 = v & 31;
    int n = n0 + row;
    float4 val = make_float4(0.f, 0.f, 0.f, 0.f);
    if (n < N) val = ((const float4*)x)[(size_t)n * 32 + c4];
    // swizzle column-group by (row>>2)&3 so the 4 ng-rows a wave reads for a
    // fixed k land in distinct banks
    *(float4*)&xs[row * 128 + ((c4 ^ ((row >> 2) & 3)) << 2)] = val;
  }
  __syncthreads();

  const int cg = tid & 15;   // 16 groups * 4 channels = 64
  const int ng = tid >> 4;   // 16 groups * 4 nodes    = 64
  const int ngm = ng & 3;
  float acc[4][4] = {};

#pragma unroll 4
  for (int k4 = 0; k4 < 32; k4++) {
    float4 xa[4], wv[4];
#pragma unroll
    for (int i = 0; i < 4; i++)
      xa[i] = *(const float4*)&xs[(ng * 4 + i) * 128 + ((k4 ^ ngm) << 2)];
#pragma unroll
    for (int kk = 0; kk < 4; kk++)
      wv[kk] = *(const float4*)&w1s[(k4 * 4 + kk) * 64 + cg * 4];
#pragma unroll
    for (int i = 0; i < 4; i++) {
#pragma unroll
      for (int kk = 0; kk < 4; kk++) {
        float a = (kk == 0) ? xa[i].x : (kk == 1) ? xa[i].y : (kk == 2) ? xa[i].z : xa[i].w;
        acc[i][0] += a * wv[kk].x;
        acc[i][1] += a * wv[kk].y;
        acc[i][2] += a * wv[kk].z;
        acc[i][3] += a * wv[kk].w;
      }
    }
  }

#pragma unroll
  for (int i = 0; i < 4; i++) {
    int n = n0 + ng * 4 + i;
    if (n >= N) continue;
    float dv = dinv[n];
    float d2 = dv * dv;
    float4 h = make_float4(acc[i][0], acc[i][1], acc[i][2], acc[i][3]);
    ((float4*)hpre1)[(size_t)n * 16 + cg] = h;
    ((float4*)agg1)[(size_t)n * 16 + cg] =
        make_float4(h.x * d2, h.y * d2, h.z * d2, h.w * d2);
  }
}

// ---------------------------------------------------------------------------
// Edge aggregation, 64 channels: one wave per edge, lane = channel.
// agg[dst][c] += h[src][c] * dinv[src]*dinv[dst]
// ---------------------------------------------------------------------------
__global__ __launch_bounds__(WG) void k_agg64(const int* __restrict__ src,
                                              const int* __restrict__ dst,
                                              const float* __restrict__ dinv,
                                              const float* __restrict__ h,
                                              float* __restrict__ agg, int E) {
  int gid = blockIdx.x * WG + threadIdx.x;
  int e = gid >> 6;
  int lane = threadIdx.x & 63;
  if (e >= E) return;
  int s = src[e], d = dst[e];
  float w = dinv[s] * dinv[d];
  atomicAdd(&agg[(size_t)d * 64 + lane], h[(size_t)s * 64 + lane] * w);
}

// 32-channel variant: half-wave per edge
__global__ __launch_bounds__(WG) void k_agg32(const int* __restrict__ src,
                                              const int* __restrict__ dst,
                                              const float* __restrict__ dinv,
                                              const float* __restrict__ h,
                                              float* __restrict__ agg, int E) {
  int gid = blockIdx.x * WG + threadIdx.x;
  int e = gid >> 5;
  int lane = threadIdx.x & 31;
  if (e >= E) return;
  int s = src[e], d = dst[e];
  float w = dinv[s] * dinv[d];
  atomicAdd(&agg[(size_t)d * 32 + lane], h[(size_t)s * 32 + lane] * w);
}

// ---------------------------------------------------------------------------
// GEMM2: hpre2[n][32] = relu(agg1[n][64] + b1) @ W2[64][32]
// Epilogue writes hpre2 AND agg2 = hpre2 * dinv^2 (self-loop init).
// ---------------------------------------------------------------------------
__global__ __launch_bounds__(WG) void k_gemm2(const float* __restrict__ agg1,
                                              const float* __restrict__ b1,
                                              const float* __restrict__ W2,
                                              const float* __restrict__ dinv,
                                              float* __restrict__ hpre2,
                                              float* __restrict__ agg2, int N) {
  __shared__ float as[64 * 68];
  __shared__ float w2s[64 * 32];
  const int tid = threadIdx.x;
  const int n0 = blockIdx.x * 64;

  for (int v = tid; v < 512; v += WG)
    *(float4*)&w2s[v * 4] = ((const float4*)W2)[v];
  for (int v = tid; v < 1024; v += WG) {
    int row = v >> 4, c4 = v & 15;
    int n = n0 + row;
    float4 val = make_float4(0.f, 0.f, 0.f, 0.f);
    if (n < N) {
      float4 g = ((const float4*)agg1)[(size_t)n * 16 + c4];
      float4 bb = ((const float4*)b1)[c4];
      val.x = fmaxf(g.x + bb.x, 0.f);
      val.y = fmaxf(g.y + bb.y, 0.f);
      val.z = fmaxf(g.z + bb.z, 0.f);
      val.w = fmaxf(g.w + bb.w, 0.f);
    }
    *(float4*)&as[row * 68 + c4 * 4] = val;
  }
  __syncthreads();

  const int cg = tid & 15;   // 16 groups * 2 channels = 32
  const int ng = tid >> 4;   // 16 groups * 4 nodes    = 64
  float acc[4][2] = {};

#pragma unroll 4
  for (int k4 = 0; k4 < 16; k4++) {
    float4 xa[4];
    float2 wv[4];
#pragma unroll
    for (int i = 0; i < 4; i++)
      xa[i] = *(const float4*)&as[(ng * 4 + i) * 68 + k4 * 4];
#pragma unroll
    for (int kk = 0; kk < 4; kk++)
      wv[kk] = *(const float2*)&w2s[(k4 * 4 + kk) * 32 + cg * 2];
#pragma unroll
    for (int i = 0; i < 4; i++) {
#pragma unroll
      for (int kk = 0; kk < 4; kk++) {
        float a = (kk == 0) ? xa[i].x : (kk == 1) ? xa[i].y : (kk == 2) ? xa[i].z : xa[i].w;
        acc[i][0] += a * wv[kk].x;
        acc[i][1] += a * wv[kk].y;
      }
    }
  }

#pragma unroll
  for (int i = 0; i < 4; i++) {
    int n = n0 + ng * 4 + i;
    if (n >= N) continue;
    float dv = dinv[n];
    float d2 = dv * dv;
    float2 h = make_float2(acc[i][0], acc[i][1]);
    ((float2*)hpre2)[(size_t)n * 16 + cg] = h;
    ((float2*)agg2)[(size_t)n * 16 + cg] = make_float2(h.x * d2, h.y * d2);
  }
}

// ---------------------------------------------------------------------------
// Final: out[n][2] = (relu(relu(agg2[n]+b2) @ fc_w + fc_b)) @ out_w + out_b
// One thread per node; agg2 tile staged in LDS (pad 33 -> conflict-free).
// ---------------------------------------------------------------------------
__global__ __launch_bounds__(WG) void k_final(const float* __restrict__ agg2,
                                              const float* __restrict__ b2,
                                              const float* __restrict__ fc_w,
                                              const float* __restrict__ fc_b,
                                              const float* __restrict__ out_w,
                                              const float* __restrict__ out_b,
                                              float* __restrict__ out, int N) {
  __shared__ float hs[256 * 33];
  __shared__ float fcs[32 * 32];
  __shared__ float b2s[32], fcbs[32], ows[64];
  const int tid = threadIdx.x;
  const int n0 = blockIdx.x * 256;

  ((float4*)fcs)[tid] = ((const float4*)fc_w)[tid];  // 256 f4 = 1024 floats
  if (tid < 32) {
    b2s[tid] = b2[tid];
    fcbs[tid] = fc_b[tid];
  }
  if (tid < 64) ows[tid] = out_w[tid];
  for (int v = tid; v < 2048; v += WG) {
    int row = v >> 3, c4 = v & 7;
    int n = n0 + row;
    float4 val = make_float4(0.f, 0.f, 0.f, 0.f);
    if (n < N) val = ((const float4*)agg2)[(size_t)n * 8 + c4];
    float* p = &hs[row * 33 + c4 * 4];
    p[0] = val.x; p[1] = val.y; p[2] = val.z; p[3] = val.w;
  }
  __syncthreads();

  int n = n0 + tid;
  float acc[32] = {};
  const int base = tid * 33;
#pragma unroll
  for (int k = 0; k < 32; k++) {
    float vk = fmaxf(hs[base + k] + b2s[k], 0.f);
#pragma unroll
    for (int j4 = 0; j4 < 8; j4++) {
      float4 f = *(const float4*)&fcs[k * 32 + j4 * 4];
      acc[j4 * 4 + 0] += vk * f.x;
      acc[j4 * 4 + 1] += vk * f.y;
      acc[j4 * 4 + 2] += vk * f.z;
      acc[j4 * 4 + 3] += vk * f.w;
    }
  }
  float o0 = out_b[0], o1 = out_b[1];
#pragma unroll
  for (int j = 0; j < 32; j++) {
    float t = fmaxf(acc[j] + fcbs[j], 0.f);
    o0 += t * ows[2 * j];
    o1 += t * ows[2 * j + 1];
  }
  if (n < N) ((float2*)out)[n] = make_float2(o0, o1);
}

// ---------------------------------------------------------------------------
extern "C" void kernel_launch(void* const* d_in, const int* in_sizes, int n_in,
                              void* d_out, int out_size, void* d_ws, size_t ws_size,
                              hipStream_t stream) {
  const float* x   = (const float*)d_in[0];
  const int*   ei  = (const int*)d_in[1];
  const float* W1  = (const float*)d_in[2];
  const float* b1  = (const float*)d_in[3];
  const float* W2  = (const float*)d_in[4];
  const float* b2  = (const float*)d_in[5];
  const float* fcw = (const float*)d_in[6];
  const float* fcb = (const float*)d_in[7];
  const float* ow  = (const float*)d_in[8];
  const float* ob  = (const float*)d_in[9];

  const int N = in_sizes[0] / 128;
  const int E = in_sizes[1] / 2;

  // workspace layout (all 16B-aligned): flag | src32 | dst32 | deg | dinv |
  // hpre1(64N) | agg1(64N) | hpre2(32N).  agg2 aliases hpre1 (dead by then).
  char* wsb = (char*)d_ws;
  int* flag  = (int*)wsb;
  int* src32 = (int*)(wsb + 256);
  int* dst32 = src32 + E;
  float* deg   = (float*)(dst32 + E);
  float* dinv  = deg + N;
  float* hpre1 = dinv + N;
  float* agg1  = hpre1 + (size_t)N * 64;
  float* hpre2 = agg1 + (size_t)N * 64;
  float* agg2  = hpre1;  // alias
  float* out = (float*)d_out;

  hipLaunchKernelGGL(k_detect, dim3(1), dim3(WG), 0, stream,
                     (const unsigned int*)ei, flag);
  hipLaunchKernelGGL(k_convert, dim3((E + WG - 1) / WG), dim3(WG), 0, stream,
                     ei, flag, src32, dst32, E);
  hipLaunchKernelGGL(k_deg_init, dim3((N + WG - 1) / WG), dim3(WG), 0, stream,
                     deg, N);
  hipLaunchKernelGGL(k_deg_count, dim3((E + WG - 1) / WG), dim3(WG), 0, stream,
                     dst32, deg, E);
  hipLaunchKernelGGL(k_dinv, dim3((N + WG - 1) / WG), dim3(WG), 0, stream,
                     deg, dinv, N);
  hipLaunchKernelGGL(k_gemm1, dim3((N + 63) / 64), dim3(WG), 0, stream,
                     x, W1, dinv, hpre1, agg1, N);
  {
    long long tot = (long long)E * 64;
    hipLaunchKernelGGL(k_agg64, dim3((int)((tot + WG - 1) / WG)), dim3(WG), 0,
                       stream, src32, dst32, dinv, hpre1, agg1, E);
  }
  hipLaunchKernelGGL(k_gemm2, dim3((N + 63) / 64), dim3(WG), 0, stream,
                     agg1, b1, W2, dinv, hpre2, agg2, N);
  {
    long long tot = (long long)E * 32;
    hipLaunchKernelGGL(k_agg32, dim3((int)((tot + WG - 1) / WG)), dim3(WG), 0,
                       stream, src32, dst32, dinv, hpre2, agg2, E);
  }
  hipLaunchKernelGGL(k_final, dim3((N + 255) / 256), dim3(WG), 0, stream,
                     agg2, b2, fcw, fcb, ow, ob, out, N);
}

// Round 2
// 684.457 us; speedup vs baseline: 1.8636x; 1.8636x over previous
//
#include <hip/hip_runtime.h>

#define WG 256

// ---------------------------------------------------------------------------
// Edge-index dtype probe: if input is int64 (little-endian, values < 2^31),
// every odd 32-bit word of the first 256 entries is 0.
// ---------------------------------------------------------------------------
__global__ __launch_bounds__(WG) void k_detect(const unsigned int* __restrict__ ei,
                                               int* __restrict__ flag) {
  __shared__ int nz;
  if (threadIdx.x == 0) nz = 0;
  __syncthreads();
  unsigned int w = ei[threadIdx.x * 2 + 1];
  if (w != 0u) atomicAdd(&nz, 1);
  __syncthreads();
  if (threadIdx.x == 0) *flag = (nz == 0) ? 1 : 0;  // 1 => int64 layout
}

// convert to int32 src/dst AND histogram in-degree (cnt must be pre-zeroed)
__global__ __launch_bounds__(WG) void k_convert(const int* __restrict__ ei,
                                                const int* __restrict__ flag,
                                                int* __restrict__ src,
                                                int* __restrict__ dst,
                                                int* __restrict__ cnt, int E) {
  int e = blockIdx.x * WG + threadIdx.x;
  if (e >= E) return;
  int s, d;
  if (*flag) {  // int64: low words at 2*idx
    s = ei[2 * e];
    d = ei[2 * (E + e)];
  } else {
    s = ei[e];
    d = ei[E + e];
  }
  src[e] = s;
  dst[e] = d;
  atomicAdd(&cnt[d], 1);
}

// ---------------------------------------------------------------------------
// Exclusive scan of cnt[N] -> rowptr[N] (3 kernels; B = ceil(N/256) <= 1024)
// ---------------------------------------------------------------------------
__global__ __launch_bounds__(WG) void k_scan1(const int* __restrict__ cnt,
                                              int* __restrict__ rowptr,
                                              int* __restrict__ partial, int N) {
  __shared__ int sh[WG];
  int i = blockIdx.x * WG + threadIdx.x;
  int v = (i < N) ? cnt[i] : 0;
  sh[threadIdx.x] = v;
  __syncthreads();
  for (int off = 1; off < WG; off <<= 1) {
    int t = (threadIdx.x >= off) ? sh[threadIdx.x - off] : 0;
    __syncthreads();
    sh[threadIdx.x] += t;
    __syncthreads();
  }
  if (i < N) rowptr[i] = sh[threadIdx.x] - v;  // block-local exclusive
  if (threadIdx.x == WG - 1) partial[blockIdx.x] = sh[WG - 1];
}

__global__ __launch_bounds__(1024) void k_scan2(int* __restrict__ partial, int B,
                                                int* __restrict__ rowptr_end, int E) {
  __shared__ int sh[1024];
  int v = (threadIdx.x < B) ? partial[threadIdx.x] : 0;
  sh[threadIdx.x] = v;
  __syncthreads();
  for (int off = 1; off < 1024; off <<= 1) {
    int t = (threadIdx.x >= off) ? sh[threadIdx.x - off] : 0;
    __syncthreads();
    sh[threadIdx.x] += t;
    __syncthreads();
  }
  if (threadIdx.x < B) partial[threadIdx.x] = sh[threadIdx.x] - v;  // exclusive
  if (threadIdx.x == 0) *rowptr_end = E;  // rowptr[N]
}

// finalize rowptr; init cursor (=cnt array reused) and dinv
__global__ __launch_bounds__(WG) void k_scan3(int* __restrict__ rowptr,
                                              const int* __restrict__ partial,
                                              int* __restrict__ cursor,
                                              float* __restrict__ dinv, int N) {
  int i = blockIdx.x * WG + threadIdx.x;
  if (i >= N) return;
  int c = cursor[i];  // cursor aliases cnt: read count BEFORE overwrite
  int rp = rowptr[i] + partial[blockIdx.x];
  rowptr[i] = rp;
  cursor[i] = rp;
  dinv[i] = rsqrtf((float)(c + 1));  // +1 = self-loop
}

// counting-sort scatter: perm[] holds src indices grouped by dst
__global__ __launch_bounds__(WG) void k_scatter(const int* __restrict__ src,
                                                const int* __restrict__ dst,
                                                int* __restrict__ cursor,
                                                int* __restrict__ perm, int E) {
  int e = blockIdx.x * WG + threadIdx.x;
  if (e >= E) return;
  int d = dst[e];
  int pos = atomicAdd(&cursor[d], 1);
  perm[pos] = src[e];
}

// ---------------------------------------------------------------------------
// GEMM1: ht1[n][64] = (x[n][128] @ W1[128][64]) * dinv[n]
// ---------------------------------------------------------------------------
__global__ __launch_bounds__(WG) void k_gemm1(const float* __restrict__ x,
                                              const float* __restrict__ W1,
                                              const float* __restrict__ dinv,
                                              float* __restrict__ ht1, int N) {
  __shared__ float xs[64 * 128];
  __shared__ float w1s[128 * 64];
  const int tid = threadIdx.x;
  const int n0 = blockIdx.x * 64;

  for (int v = tid; v < 2048; v += WG)
    *(float4*)&w1s[v * 4] = ((const float4*)W1)[v];
  for (int v = tid; v < 2048; v += WG) {
    int row = v >> 5, c4 = v & 31;
    int n = n0 + row;
    float4 val = make_float4(0.f, 0.f, 0.f, 0.f);
    if (n < N) val = ((const float4*)x)[(size_t)n * 32 + c4];
    *(float4*)&xs[row * 128 + ((c4 ^ ((row >> 2) & 3)) << 2)] = val;
  }
  __syncthreads();

  const int cg = tid & 15;
  const int ng = tid >> 4;
  const int ngm = ng & 3;
  float acc[4][4] = {};

#pragma unroll 4
  for (int k4 = 0; k4 < 32; k4++) {
    float4 xa[4], wv[4];
#pragma unroll
    for (int i = 0; i < 4; i++)
      xa[i] = *(const float4*)&xs[(ng * 4 + i) * 128 + ((k4 ^ ngm) << 2)];
#pragma unroll
    for (int kk = 0; kk < 4; kk++)
      wv[kk] = *(const float4*)&w1s[(k4 * 4 + kk) * 64 + cg * 4];
#pragma unroll
    for (int i = 0; i < 4; i++) {
#pragma unroll
      for (int kk = 0; kk < 4; kk++) {
        float a = (kk == 0) ? xa[i].x : (kk == 1) ? xa[i].y : (kk == 2) ? xa[i].z : xa[i].w;
        acc[i][0] += a * wv[kk].x;
        acc[i][1] += a * wv[kk].y;
        acc[i][2] += a * wv[kk].z;
        acc[i][3] += a * wv[kk].w;
      }
    }
  }

#pragma unroll
  for (int i = 0; i < 4; i++) {
    int n = n0 + ng * 4 + i;
    if (n >= N) continue;
    float dv = dinv[n];
    ((float4*)ht1)[(size_t)n * 16 + cg] = make_float4(
        acc[i][0] * dv, acc[i][1] * dv, acc[i][2] * dv, acc[i][3] * dv);
  }
}

// ---------------------------------------------------------------------------
// CSR aggregation, 64 ch: one wave per node, lane = channel.
// agg[n] = dinv[n] * (ht[n] + sum_{s in CSR(n)} ht[s])
// ---------------------------------------------------------------------------
__global__ __launch_bounds__(WG) void k_aggcsr64(const int* __restrict__ rowptr,
                                                 const int* __restrict__ perm,
                                                 const float* __restrict__ dinv,
                                                 const float* __restrict__ ht,
                                                 float* __restrict__ agg, int N) {
  int n = (blockIdx.x * WG + threadIdx.x) >> 6;
  int lane = threadIdx.x & 63;
  if (n >= N) return;
  int beg = rowptr[n], end = rowptr[n + 1];
  float acc = ht[(size_t)n * 64 + lane];
  int j = beg;
  for (; j + 4 <= end; j += 4) {
    int s0 = perm[j], s1 = perm[j + 1], s2 = perm[j + 2], s3 = perm[j + 3];
    float v0 = ht[(size_t)s0 * 64 + lane];
    float v1 = ht[(size_t)s1 * 64 + lane];
    float v2 = ht[(size_t)s2 * 64 + lane];
    float v3 = ht[(size_t)s3 * 64 + lane];
    acc += v0 + v1 + v2 + v3;
  }
  for (; j < end; ++j) acc += ht[(size_t)perm[j] * 64 + lane];
  agg[(size_t)n * 64 + lane] = acc * dinv[n];
}

// 32-ch variant: half-wave per node (two nodes per wave)
__global__ __launch_bounds__(WG) void k_aggcsr32(const int* __restrict__ rowptr,
                                                 const int* __restrict__ perm,
                                                 const float* __restrict__ dinv,
                                                 const float* __restrict__ ht,
                                                 float* __restrict__ agg, int N) {
  int n = (blockIdx.x * WG + threadIdx.x) >> 5;
  int l = threadIdx.x & 31;
  if (n >= N) return;
  int beg = rowptr[n], end = rowptr[n + 1];
  float acc = ht[(size_t)n * 32 + l];
  int j = beg;
  for (; j + 4 <= end; j += 4) {
    int s0 = perm[j], s1 = perm[j + 1], s2 = perm[j + 2], s3 = perm[j + 3];
    acc += ht[(size_t)s0 * 32 + l] + ht[(size_t)s1 * 32 + l] +
           ht[(size_t)s2 * 32 + l] + ht[(size_t)s3 * 32 + l];
  }
  for (; j < end; ++j) acc += ht[(size_t)perm[j] * 32 + l];
  agg[(size_t)n * 32 + l] = acc * dinv[n];
}

// ---------------------------------------------------------------------------
// GEMM2: ht2[n][32] = (relu(agg1[n][64] + b1) @ W2[64][32]) * dinv[n]
// ---------------------------------------------------------------------------
__global__ __launch_bounds__(WG) void k_gemm2(const float* __restrict__ agg1,
                                              const float* __restrict__ b1,
                                              const float* __restrict__ W2,
                                              const float* __restrict__ dinv,
                                              float* __restrict__ ht2, int N) {
  __shared__ float as[64 * 68];
  __shared__ float w2s[64 * 32];
  const int tid = threadIdx.x;
  const int n0 = blockIdx.x * 64;

  for (int v = tid; v < 512; v += WG)
    *(float4*)&w2s[v * 4] = ((const float4*)W2)[v];
  for (int v = tid; v < 1024; v += WG) {
    int row = v >> 4, c4 = v & 15;
    int n = n0 + row;
    float4 val = make_float4(0.f, 0.f, 0.f, 0.f);
    if (n < N) {
      float4 g = ((const float4*)agg1)[(size_t)n * 16 + c4];
      float4 bb = ((const float4*)b1)[c4];
      val.x = fmaxf(g.x + bb.x, 0.f);
      val.y = fmaxf(g.y + bb.y, 0.f);
      val.z = fmaxf(g.z + bb.z, 0.f);
      val.w = fmaxf(g.w + bb.w, 0.f);
    }
    *(float4*)&as[row * 68 + c4 * 4] = val;
  }
  __syncthreads();

  const int cg = tid & 15;
  const int ng = tid >> 4;
  float acc[4][2] = {};

#pragma unroll 4
  for (int k4 = 0; k4 < 16; k4++) {
    float4 xa[4];
    float2 wv[4];
#pragma unroll
    for (int i = 0; i < 4; i++)
      xa[i] = *(const float4*)&as[(ng * 4 + i) * 68 + k4 * 4];
#pragma unroll
    for (int kk = 0; kk < 4; kk++)
      wv[kk] = *(const float2*)&w2s[(k4 * 4 + kk) * 32 + cg * 2];
#pragma unroll
    for (int i = 0; i < 4; i++) {
#pragma unroll
      for (int kk = 0; kk < 4; kk++) {
        float a = (kk == 0) ? xa[i].x : (kk == 1) ? xa[i].y : (kk == 2) ? xa[i].z : xa[i].w;
        acc[i][0] += a * wv[kk].x;
        acc[i][1] += a * wv[kk].y;
      }
    }
  }

#pragma unroll
  for (int i = 0; i < 4; i++) {
    int n = n0 + ng * 4 + i;
    if (n >= N) continue;
    float dv = dinv[n];
    ((float2*)ht2)[(size_t)n * 16 + cg] =
        make_float2(acc[i][0] * dv, acc[i][1] * dv);
  }
}

// ---------------------------------------------------------------------------
// Final: out[n][2] = (relu(relu(agg2[n]+b2) @ fc_w + fc_b)) @ out_w + out_b
// ---------------------------------------------------------------------------
__global__ __launch_bounds__(WG) void k_final(const float* __restrict__ agg2,
                                              const float* __restrict__ b2,
                                              const float* __restrict__ fc_w,
                                              const float* __restrict__ fc_b,
                                              const float* __restrict__ out_w,
                                              const float* __restrict__ out_b,
                                              float* __restrict__ out, int N) {
  __shared__ float hs[256 * 33];
  __shared__ float fcs[32 * 32];
  __shared__ float b2s[32], fcbs[32], ows[64];
  const int tid = threadIdx.x;
  const int n0 = blockIdx.x * 256;

  ((float4*)fcs)[tid] = ((const float4*)fc_w)[tid];
  if (tid < 32) {
    b2s[tid] = b2[tid];
    fcbs[tid] = fc_b[tid];
  }
  if (tid < 64) ows[tid] = out_w[tid];
  for (int v = tid; v < 2048; v += WG) {
    int row = v >> 3, c4 = v & 7;
    int n = n0 + row;
    float4 val = make_float4(0.f, 0.f, 0.f, 0.f);
    if (n < N) val = ((const float4*)agg2)[(size_t)n * 8 + c4];
    float* p = &hs[row * 33 + c4 * 4];
    p[0] = val.x; p[1] = val.y; p[2] = val.z; p[3] = val.w;
  }
  __syncthreads();

  int n = n0 + tid;
  float acc[32] = {};
  const int base = tid * 33;
#pragma unroll
  for (int k = 0; k < 32; k++) {
    float vk = fmaxf(hs[base + k] + b2s[k], 0.f);
#pragma unroll
    for (int j4 = 0; j4 < 8; j4++) {
      float4 f = *(const float4*)&fcs[k * 32 + j4 * 4];
      acc[j4 * 4 + 0] += vk * f.x;
      acc[j4 * 4 + 1] += vk * f.y;
      acc[j4 * 4 + 2] += vk * f.z;
      acc[j4 * 4 + 3] += vk * f.w;
    }
  }
  float o0 = out_b[0], o1 = out_b[1];
#pragma unroll
  for (int j = 0; j < 32; j++) {
    float t = fmaxf(acc[j] + fcbs[j], 0.f);
    o0 += t * ows[2 * j];
    o1 += t * ows[2 * j + 1];
  }
  if (n < N) ((float2*)out)[n] = make_float2(o0, o1);
}

// ---------------------------------------------------------------------------
extern "C" void kernel_launch(void* const* d_in, const int* in_sizes, int n_in,
                              void* d_out, int out_size, void* d_ws, size_t ws_size,
                              hipStream_t stream) {
  const float* x   = (const float*)d_in[0];
  const int*   ei  = (const int*)d_in[1];
  const float* W1  = (const float*)d_in[2];
  const float* b1  = (const float*)d_in[3];
  const float* W2  = (const float*)d_in[4];
  const float* b2  = (const float*)d_in[5];
  const float* fcw = (const float*)d_in[6];
  const float* fcb = (const float*)d_in[7];
  const float* ow  = (const float*)d_in[8];
  const float* ob  = (const float*)d_in[9];

  const int N = in_sizes[0] / 128;
  const int E = in_sizes[1] / 2;
  const int B = (N + WG - 1) / WG;  // scan blocks (<=1024 required)

  // workspace layout:
  // flag(256B) | src32(E) dst32(E) [ht1(64N)/agg2(32N) alias here later] |
  // perm(E) | cnt(N)=cursor | rowptr(N+4) | partial(1024) | dinv(N) |
  // agg1(64N) | ht2(32N)
  char* wsb = (char*)d_ws;
  int* flag   = (int*)wsb;
  int* src32  = (int*)(wsb + 256);
  int* dst32  = src32 + E;
  int* perm   = dst32 + E;
  int* cnt    = perm + E;           // reused as cursor after scan
  int* rowptr = cnt + N;            // N+1 entries (+pad)
  int* partial = rowptr + N + 4;
  float* dinv = (float*)(partial + 1024);
  float* agg1 = dinv + N;
  float* ht2  = agg1 + (size_t)N * 64;
  float* ht1  = (float*)src32;      // alias: src/dst dead after scatter
  float* agg2 = (float*)src32;      // alias: ht1 dead after aggcsr64
  float* out  = (float*)d_out;

  hipLaunchKernelGGL(k_detect, dim3(1), dim3(WG), 0, stream,
                     (const unsigned int*)ei, flag);
  hipMemsetAsync(cnt, 0, (size_t)N * sizeof(int), stream);
  hipLaunchKernelGGL(k_convert, dim3((E + WG - 1) / WG), dim3(WG), 0, stream,
                     ei, flag, src32, dst32, cnt, E);
  hipLaunchKernelGGL(k_scan1, dim3(B), dim3(WG), 0, stream,
                     cnt, rowptr, partial, N);
  hipLaunchKernelGGL(k_scan2, dim3(1), dim3(1024), 0, stream,
                     partial, B, rowptr + N, E);
  hipLaunchKernelGGL(k_scan3, dim3(B), dim3(WG), 0, stream,
                     rowptr, partial, cnt, dinv, N);
  hipLaunchKernelGGL(k_scatter, dim3((E + WG - 1) / WG), dim3(WG), 0, stream,
                     src32, dst32, cnt, perm, E);
  hipLaunchKernelGGL(k_gemm1, dim3((N + 63) / 64), dim3(WG), 0, stream,
                     x, W1, dinv, ht1, N);
  {
    long long tot = (long long)N * 64;
    hipLaunchKernelGGL(k_aggcsr64, dim3((int)((tot + WG - 1) / WG)), dim3(WG), 0,
                       stream, rowptr, perm, dinv, ht1, agg1, N);
  }
  hipLaunchKernelGGL(k_gemm2, dim3((N + 63) / 64), dim3(WG), 0, stream,
                     agg1, b1, W2, dinv, ht2, N);
  {
    long long tot = (long long)N * 32;
    hipLaunchKernelGGL(k_aggcsr32, dim3((int)((tot + WG - 1) / WG)), dim3(WG), 0,
                       stream, rowptr, perm, dinv, ht2, agg2, N);
  }
  hipLaunchKernelGGL(k_final, dim3((N + 255) / 256), dim3(WG), 0, stream,
                     agg2, b2, fcw, fcb, ow, ob, out, N);
}